// Round 1
// baseline (762.894 us; speedup 1.0000x reference)
//
#include <hip/hip_runtime.h>

#define BATCH 8192
#define FEAT  512
#define NID   256
#define NTR   256
#define HID   1024
#define PPF   47       // params per transform feature (3*16-1)
#define PPFP  48       // padded to 48
#define NOUT  (NTR*PPF)    // 12032
#define NPAD  (NTR*PPFP)   // 12288
#define TBOUND 3.0f
#define MIN_W 0.001f
#define MIN_H 0.001f
#define MIN_D 0.001f

typedef __bf16 bf16x8 __attribute__((ext_vector_type(8)));
typedef float  f32x4  __attribute__((ext_vector_type(4)));

__device__ __forceinline__ unsigned short f2bf(float f) {
  unsigned u = __float_as_uint(f);
  u += 0x7FFFu + ((u >> 16) & 1u);   // RNE
  return (unsigned short)(u >> 16);
}

// ---------------- pack kernels ----------------

// identity split -> bf16 A1 matrix, and copy identity cols into outputs
__global__ void k_pack_inputs(const float* __restrict__ in,
                              unsigned short* __restrict__ idbf,
                              float* __restrict__ outp) {
  int b = blockIdx.x;
  int j = threadIdx.x;            // 0..255
  float v = in[b * FEAT + 2 * j + 1];
  idbf[b * NID + j] = f2bf(v);
  outp[b * FEAT + 2 * j + 1] = v;
}

// W1 [256][1024] f32 -> W1T [1024][256] bf16
__global__ void k_pack_w1t(const float* __restrict__ W1,
                           unsigned short* __restrict__ W1T) {
  __shared__ unsigned short tl[64][65];
  int n0 = blockIdx.x * 64, k0 = blockIdx.y * 64;
  int c = threadIdx.x & 63, r4 = threadIdx.x >> 6;
  #pragma unroll
  for (int i = 0; i < 16; ++i) {
    int kk = r4 + i * 4;
    tl[kk][c] = f2bf(W1[(k0 + kk) * HID + n0 + c]);
  }
  __syncthreads();
  #pragma unroll
  for (int i = 0; i < 16; ++i) {
    int nn = r4 + i * 4;
    W1T[(n0 + nn) * NID + k0 + c] = tl[c][nn];
  }
}

// W2 [1024][12032] f32 -> W2T [12288][1024] bf16 (padded: col 47 of each
// 48-group left for k_pad_w2t)
__global__ void k_pack_w2t(const float* __restrict__ W2,
                           unsigned short* __restrict__ W2T) {
  __shared__ unsigned short tl[64][65];
  int ns0 = blockIdx.x * 64, k0 = blockIdx.y * 64;
  int c = threadIdx.x & 63, r4 = threadIdx.x >> 6;
  #pragma unroll
  for (int i = 0; i < 16; ++i) {
    int kk = r4 + i * 4;
    tl[kk][c] = f2bf(W2[(k0 + kk) * (long)NOUT + ns0 + c]);
  }
  __syncthreads();
  #pragma unroll
  for (int i = 0; i < 16; ++i) {
    int nn = r4 + i * 4;
    int ns = ns0 + nn;
    int nd = (ns / PPF) * PPFP + (ns % PPF);
    W2T[(long)nd * HID + k0 + c] = tl[c][nn];
  }
}

__global__ void k_pad_w2t(unsigned short* __restrict__ W2T) {
  int idx = blockIdx.x * 256 + threadIdx.x;  // 256 features * 1024 k
  int f = idx >> 10, k = idx & 1023;
  W2T[((long)(f * PPFP + PPF)) * HID + k] = 0;
}

// ---------------- GEMM1: h = relu(idbf @ W1 + b1), bf16 out ----------------
// M=8192 K=256 N=1024, tiles 128x128, BK=64, 4 waves (2x2), wave=64x64
__global__ __launch_bounds__(256, 2) void k_gemm1(
    const unsigned short* __restrict__ A, const unsigned short* __restrict__ Bw,
    const float* __restrict__ b1, unsigned short* __restrict__ H) {
  __shared__ __align__(16) char sm[32768];  // A 16KB, B 16KB
  char* smA = sm;
  char* smB = sm + 16384;
  const int tid = threadIdx.x;
  const int lane = tid & 63, wid = tid >> 6;
  const int c = lane & 15, g = lane >> 4;
  const int wm = wid >> 1, wn = wid & 1;
  const int m0 = blockIdx.x * 128, n0 = blockIdx.y * 128;

  f32x4 zero = {0.f, 0.f, 0.f, 0.f};
  f32x4 acc[4][4];
  #pragma unroll
  for (int a = 0; a < 4; ++a)
    #pragma unroll
    for (int b = 0; b < 4; ++b) acc[a][b] = zero;

  for (int ks = 0; ks < 4; ++ks) {
    #pragma unroll
    for (int j = 0; j < 4; ++j) {           // 1024 slots each for A and B
      int s = tid + j * 256;
      int row = s >> 3, kb = s & 7;
      int4 va = *(const int4*)(A + (long)(m0 + row) * NID + ks * 64 + kb * 8);
      *(int4*)(smA + row * 128 + ((kb ^ (row & 7)) << 4)) = va;
      int4 vb = *(const int4*)(Bw + (long)(n0 + row) * NID + ks * 64 + kb * 8);
      *(int4*)(smB + row * 128 + ((kb ^ (row & 7)) << 4)) = vb;
    }
    __syncthreads();
    #pragma unroll
    for (int kk = 0; kk < 2; ++kk) {
      bf16x8 av[4], bv[4];
      int kbl = kk * 4 + g;
      #pragma unroll
      for (int mf = 0; mf < 4; ++mf) {
        int row = wm * 64 + mf * 16 + c;
        av[mf] = *(const bf16x8*)(smA + row * 128 + ((kbl ^ (row & 7)) << 4));
      }
      #pragma unroll
      for (int nf = 0; nf < 4; ++nf) {
        int col = wn * 64 + nf * 16 + c;
        bv[nf] = *(const bf16x8*)(smB + col * 128 + ((kbl ^ (col & 7)) << 4));
      }
      #pragma unroll
      for (int mf = 0; mf < 4; ++mf)
        #pragma unroll
        for (int nf = 0; nf < 4; ++nf)
          acc[mf][nf] = __builtin_amdgcn_mfma_f32_16x16x32_bf16(
              av[mf], bv[nf], acc[mf][nf], 0, 0, 0);
    }
    __syncthreads();
  }
  #pragma unroll
  for (int nf = 0; nf < 4; ++nf) {
    float bb = b1[n0 + wn * 64 + nf * 16 + c];
    #pragma unroll
    for (int mf = 0; mf < 4; ++mf) {
      #pragma unroll
      for (int i = 0; i < 4; ++i) {
        int row = m0 + wm * 64 + mf * 16 + 4 * g + i;
        int col = n0 + wn * 64 + nf * 16 + c;
        float v = acc[mf][nf][i] + bb;
        H[(long)row * HID + col] = f2bf(fmaxf(v, 0.f));
      }
    }
  }
}

// ---------------- spline on a 16-lane group ----------------
// lane c of the group holds param column c; all lanes return identical y/lad.
__device__ __noinline__ void spline16(float x, float uw, float uh, float ud,
                                      float* yo, float* lo) {
  const int lane = threadIdx.x & 63;
  const int c = lane & 15;
  const int g = lane >> 4;
  // widths softmax + scan
  float mw = uw;
  #pragma unroll
  for (int d = 1; d < 16; d <<= 1) mw = fmaxf(mw, __shfl_xor(mw, d, 16));
  float ew = __expf(uw - mw);
  float sw = ew;
  #pragma unroll
  for (int d = 1; d < 16; d <<= 1) sw += __shfl_xor(sw, d, 16);
  float w = MIN_W + (1.f - MIN_W * 16.f) * (ew / sw);
  float iw = w;
  #pragma unroll
  for (int d = 1; d < 16; d <<= 1) {
    float o = __shfl_up(iw, d, 16);
    if (c >= d) iw += o;
  }
  float kr = (c == 15) ? TBOUND : fmaf(2.f * TBOUND, iw, -TBOUND);
  float kl = (c == 0) ? -TBOUND : fmaf(2.f * TBOUND, iw - w, -TBOUND);
  float wid = kr - kl;
  // heights softmax + scan
  float mh = uh;
  #pragma unroll
  for (int d = 1; d < 16; d <<= 1) mh = fmaxf(mh, __shfl_xor(mh, d, 16));
  float eh = __expf(uh - mh);
  float sh = eh;
  #pragma unroll
  for (int d = 1; d < 16; d <<= 1) sh += __shfl_xor(sh, d, 16);
  float hgt = MIN_H + (1.f - MIN_H * 16.f) * (eh / sh);
  float ih = hgt;
  #pragma unroll
  for (int d = 1; d < 16; d <<= 1) {
    float o = __shfl_up(ih, d, 16);
    if (c >= d) ih += o;
  }
  float hr = (c == 15) ? TBOUND : fmaf(2.f * TBOUND, ih, -TBOUND);
  float hl = (c == 0) ? -TBOUND : fmaf(2.f * TBOUND, ih - hgt, -TBOUND);
  float hei = hr - hl;
  // derivatives at knots: lane c holds deriv[c+1]; deriv[0]=deriv[16]=1
  float sp = (ud > 0.f) ? (ud + log1pf(__expf(-ud))) : log1pf(__expf(ud));
  float dr = (c == 15) ? 1.0f : (MIN_D + sp);
  float dl = __shfl_up(dr, 1, 16);
  if (c == 0) dl = 1.0f;
  // bin search via ballot
  float xc = fminf(fmaxf(x, -TBOUND), TBOUND);
  unsigned long long bal = __ballot(xc >= kr);
  int idx = (int)__popcll((bal >> (g * 16)) & 0xFFFFull);
  idx = min(idx, 15);
  float in_cw = __shfl(kl, idx, 16);
  float in_w  = __shfl(wid, idx, 16);
  float in_ch = __shfl(hl, idx, 16);
  float in_h  = __shfl(hei, idx, 16);
  float d0    = __shfl(dl, idx, 16);
  float d1    = __shfl(dr, idx, 16);
  float dlt = in_h / in_w;
  float th = (xc - in_cw) / in_w;
  float omt = 1.f - th;
  float t1m = th * omt;
  float den = dlt + (d0 + d1 - 2.f * dlt) * t1m;
  float num = in_h * (dlt * th * th + d0 * t1m);
  float y = in_ch + num / den;
  float dn = dlt * dlt * (d1 * th * th + 2.f * dlt * t1m + d0 * omt * omt);
  float lad = __logf(dn) - 2.f * __logf(den);
  bool inside = (x >= -TBOUND) && (x <= TBOUND);
  *yo = inside ? y : x;
  *lo = inside ? lad : 0.f;
}

// ---------------- GEMM2 (params) fused with spline ----------------
// M=8192, Npad=12288, K=1024. Tile 256x192 (4 features), 8 waves (2x4),
// wave = 128 rows x 48 cols (1 feature => uw/uh/ud are the 3 col fragments).
__global__ __launch_bounds__(512, 2) void k_gemm2_spline(
    const unsigned short* __restrict__ Hb, const unsigned short* __restrict__ W2T,
    const float* __restrict__ b2, const float* __restrict__ inp,
    float* __restrict__ outp, float* __restrict__ ladw) {
  __shared__ __align__(16) char sm[57344];  // A 32KB @0, B 24KB @32768
  char* smA = sm;
  char* smB = sm + 32768;
  const int tid = threadIdx.x;
  const int lane = tid & 63, wid = tid >> 6;
  const int c = lane & 15, g = lane >> 4;
  const int wm = wid >> 2, wn = wid & 3;
  const long m0 = (long)blockIdx.x * 256;
  const int bn = blockIdx.y;
  const int n0 = bn * 192;  // padded-col base

  f32x4 zero = {0.f, 0.f, 0.f, 0.f};
  f32x4 acc[8][3];
  #pragma unroll
  for (int a = 0; a < 8; ++a)
    #pragma unroll
    for (int b = 0; b < 3; ++b) acc[a][b] = zero;

  for (int ks = 0; ks < 16; ++ks) {
    #pragma unroll
    for (int j = 0; j < 4; ++j) {          // A: 2048 slots (256 rows x 8)
      int s = tid + j * 512;
      int row = s >> 3, kb = s & 7;
      int4 v = *(const int4*)(Hb + (m0 + row) * 1024L + ks * 64 + kb * 8);
      *(int4*)(smA + row * 128 + ((kb ^ (row & 7)) << 4)) = v;
    }
    #pragma unroll
    for (int j = 0; j < 3; ++j) {          // B: 1536 slots (192 rows x 8)
      int s = tid + j * 512;
      int row = s >> 3, kb = s & 7;
      int4 v = *(const int4*)(W2T + (long)(n0 + row) * 1024L + ks * 64 + kb * 8);
      *(int4*)(smB + row * 128 + ((kb ^ (row & 7)) << 4)) = v;
    }
    __syncthreads();
    #pragma unroll
    for (int kk = 0; kk < 2; ++kk) {
      bf16x8 av[8], bv[3];
      int kbl = kk * 4 + g;
      #pragma unroll
      for (int mf = 0; mf < 8; ++mf) {
        int row = wm * 128 + mf * 16 + c;
        av[mf] = *(const bf16x8*)(smA + row * 128 + ((kbl ^ (row & 7)) << 4));
      }
      #pragma unroll
      for (int nf = 0; nf < 3; ++nf) {
        int col = wn * 48 + nf * 16 + c;
        bv[nf] = *(const bf16x8*)(smB + col * 128 + ((kbl ^ (col & 7)) << 4));
      }
      #pragma unroll
      for (int mf = 0; mf < 8; ++mf)
        #pragma unroll
        for (int nf = 0; nf < 3; ++nf)
          acc[mf][nf] = __builtin_amdgcn_mfma_f32_16x16x32_bf16(
              av[mf], bv[nf], acc[mf][nf], 0, 0, 0);
    }
    __syncthreads();
  }

  // epilogue: spline per row of this wave's feature
  const int t = bn * 4 + wn;               // global transform-feature id
  const float* b2t = b2 + t * PPF;
  float bw = b2t[c];
  float bh = b2t[16 + c];
  float bd = (c < 15) ? b2t[32 + c] : 0.f;
  #pragma unroll
  for (int mf = 0; mf < 8; ++mf) {
    #pragma unroll
    for (int i = 0; i < 4; ++i) {
      long r = m0 + wm * 128 + mf * 16 + 4 * g + i;
      float x = inp[r * FEAT + 2 * t];
      float y, lad;
      spline16(x, acc[mf][0][i] + bw, acc[mf][1][i] + bh, acc[mf][2][i] + bd,
               &y, &lad);
      if (c == 0) {
        outp[r * FEAT + 2 * t] = y;
        ladw[r * NTR + t] = lad;
      }
    }
  }
}

// ---------------- lad reduction: 256 -> 1 per batch row ----------------
__global__ void k_reduce_lad(const float* __restrict__ ladw,
                             float* __restrict__ lado) {
  int wid = threadIdx.x >> 6, lane = threadIdx.x & 63;
  long b = (long)blockIdx.x * 4 + wid;
  const float4* p = (const float4*)(ladw + b * NTR);
  float4 v = p[lane];
  float s = v.x + v.y + v.z + v.w;
  #pragma unroll
  for (int d = 1; d < 64; d <<= 1) s += __shfl_xor(s, d, 64);
  if (lane == 0) lado[b] = s;
}

extern "C" void kernel_launch(void* const* d_in, const int* in_sizes, int n_in,
                              void* d_out, int out_size, void* d_ws, size_t ws_size,
                              hipStream_t stream) {
  const float* inp = (const float*)d_in[0];
  const float* W1  = (const float*)d_in[1];
  const float* b1  = (const float*)d_in[2];
  const float* W2  = (const float*)d_in[3];
  const float* b2  = (const float*)d_in[4];
  float* outp = (float*)d_out;
  float* lado = outp + (long)BATCH * FEAT;

  // workspace layout (needs ~52.5 MB)
  char* ws = (char*)d_ws;
  unsigned short* Hb   = (unsigned short*)(ws);              // 16,777,216 B
  unsigned short* idbf = (unsigned short*)(ws + 16777216);   //  4,194,304 B
  unsigned short* W1T  = (unsigned short*)(ws + 20971520);   //    524,288 B
  unsigned short* W2T  = (unsigned short*)(ws + 21495808);   // 25,165,824 B
  float*          ladw = (float*)(ws + 46661632);            //  8,388,608 B

  k_pack_inputs<<<dim3(BATCH), dim3(256), 0, stream>>>(inp, idbf, outp);
  k_pack_w1t<<<dim3(16, 4), dim3(256), 0, stream>>>(W1, W1T);
  k_pack_w2t<<<dim3(188, 16), dim3(256), 0, stream>>>(W2, W2T);
  k_pad_w2t<<<dim3(1024), dim3(256), 0, stream>>>(W2T);
  k_gemm1<<<dim3(64, 8), dim3(256), 0, stream>>>(idbf, W1T, b1, Hb);
  k_gemm2_spline<<<dim3(32, 64), dim3(512), 0, stream>>>(Hb, W2T, b2, inp, outp, ladw);
  k_reduce_lad<<<dim3(2048), dim3(256), 0, stream>>>(ladw, lado);
}

// Round 2
// 491.979 us; speedup vs baseline: 1.5507x; 1.5507x over previous
//
#include <hip/hip_runtime.h>

#define BATCH 8192
#define FEAT  512
#define NID   256
#define NTR   256
#define HID   1024
#define PPF   47       // params per transform feature (3*16-1)
#define PPFP  48       // padded to 48
#define NOUT  (NTR*PPF)    // 12032
#define TBOUND 3.0f
#define MIN_W 0.001f
#define MIN_H 0.001f
#define MIN_D 0.001f

typedef __bf16 bf16x8 __attribute__((ext_vector_type(8)));
typedef float  f32x4  __attribute__((ext_vector_type(4)));

__device__ __forceinline__ unsigned short f2bf(float f) {
  unsigned u = __float_as_uint(f);
  u += 0x7FFFu + ((u >> 16) & 1u);   // RNE
  return (unsigned short)(u >> 16);
}

// async global->LDS, 16B per lane. LDS dest must be wave-uniform base
// (HW adds lane*16); global source is per-lane.
__device__ __forceinline__ void gload16(const void* g, void* l) {
  __builtin_amdgcn_global_load_lds(
      (const __attribute__((address_space(1))) void*)g,
      (__attribute__((address_space(3))) void*)l, 16, 0, 0);
}

// ---------------- pack kernels ----------------

__global__ void k_pack_inputs(const float* __restrict__ in,
                              unsigned short* __restrict__ idbf,
                              float* __restrict__ outp) {
  int b = blockIdx.x;
  int j = threadIdx.x;            // 0..255
  float v = in[b * FEAT + 2 * j + 1];
  idbf[b * NID + j] = f2bf(v);
  outp[b * FEAT + 2 * j + 1] = v;
}

// W1 [256][1024] f32 -> W1T [1024][256] bf16
__global__ void k_pack_w1t(const float* __restrict__ W1,
                           unsigned short* __restrict__ W1T) {
  __shared__ unsigned short tl[64][65];
  int n0 = blockIdx.x * 64, k0 = blockIdx.y * 64;
  int c = threadIdx.x & 63, r4 = threadIdx.x >> 6;
  #pragma unroll
  for (int i = 0; i < 16; ++i) {
    int kk = r4 + i * 4;
    tl[kk][c] = f2bf(W1[(k0 + kk) * HID + n0 + c]);
  }
  __syncthreads();
  #pragma unroll
  for (int i = 0; i < 16; ++i) {
    int nn = r4 + i * 4;
    W1T[(n0 + nn) * NID + k0 + c] = tl[c][nn];
  }
}

// W2 [1024][12032] f32 -> W2T [12288][1024] bf16 (padded)
__global__ void k_pack_w2t(const float* __restrict__ W2,
                           unsigned short* __restrict__ W2T) {
  __shared__ unsigned short tl[64][65];
  int ns0 = blockIdx.x * 64, k0 = blockIdx.y * 64;
  int c = threadIdx.x & 63, r4 = threadIdx.x >> 6;
  #pragma unroll
  for (int i = 0; i < 16; ++i) {
    int kk = r4 + i * 4;
    tl[kk][c] = f2bf(W2[(k0 + kk) * (long)NOUT + ns0 + c]);
  }
  __syncthreads();
  #pragma unroll
  for (int i = 0; i < 16; ++i) {
    int nn = r4 + i * 4;
    int ns = ns0 + nn;
    int nd = (ns / PPF) * PPFP + (ns % PPF);
    W2T[(long)nd * HID + k0 + c] = tl[c][nn];
  }
}

__global__ void k_pad_w2t(unsigned short* __restrict__ W2T) {
  int idx = blockIdx.x * 256 + threadIdx.x;  // 256 features * 1024 k
  int f = idx >> 10, k = idx & 1023;
  W2T[((long)(f * PPFP + PPF)) * HID + k] = 0;
}

// ---------------- GEMM1: h = relu(idbf @ W1 + b1), bf16 out ----------------
// M=8192 K=256 N=1024, tiles 128x128, BK=64, 4 waves (2x2)
__global__ __launch_bounds__(256, 2) void k_gemm1(
    const unsigned short* __restrict__ A, const unsigned short* __restrict__ Bw,
    const float* __restrict__ b1, unsigned short* __restrict__ H) {
  __shared__ __align__(16) char sm[32768];  // A 16KB, B 16KB
  char* smA = sm;
  char* smB = sm + 16384;
  const int tid = threadIdx.x;
  const int lane = tid & 63, wid = tid >> 6;
  const int c = lane & 15, g = lane >> 4;
  const int wm = wid >> 1, wn = wid & 1;
  const int m0 = blockIdx.x * 128, n0 = blockIdx.y * 128;

  f32x4 zero = {0.f, 0.f, 0.f, 0.f};
  f32x4 acc[4][4];
  #pragma unroll
  for (int a = 0; a < 4; ++a)
    #pragma unroll
    for (int b = 0; b < 4; ++b) acc[a][b] = zero;

  for (int ks = 0; ks < 4; ++ks) {
    #pragma unroll
    for (int j = 0; j < 4; ++j) {           // 1024 slots each for A and B
      int s0 = j * 256 + wid * 64;
      int s = s0 + lane;
      int row = s >> 3, kb = (s & 7) ^ (row & 7);   // pre-swizzled source
      gload16(A + (long)(m0 + row) * NID + ks * 64 + kb * 8, smA + s0 * 16);
      gload16(Bw + (long)(n0 + row) * NID + ks * 64 + kb * 8, smB + s0 * 16);
    }
    __syncthreads();
    #pragma unroll
    for (int kk = 0; kk < 2; ++kk) {
      bf16x8 av[4], bv[4];
      int kbl = kk * 4 + g;
      #pragma unroll
      for (int mf = 0; mf < 4; ++mf) {
        int row = wm * 64 + mf * 16 + c;
        av[mf] = *(const bf16x8*)(smA + row * 128 + ((kbl ^ (row & 7)) << 4));
      }
      #pragma unroll
      for (int nf = 0; nf < 4; ++nf) {
        int col = wn * 64 + nf * 16 + c;
        bv[nf] = *(const bf16x8*)(smB + col * 128 + ((kbl ^ (col & 7)) << 4));
      }
      #pragma unroll
      for (int mf = 0; mf < 4; ++mf)
        #pragma unroll
        for (int nf = 0; nf < 4; ++nf)
          acc[mf][nf] = __builtin_amdgcn_mfma_f32_16x16x32_bf16(
              av[mf], bv[nf], acc[mf][nf], 0, 0, 0);
    }
    __syncthreads();
  }
  #pragma unroll
  for (int nf = 0; nf < 4; ++nf) {
    float bb = b1[n0 + wn * 64 + nf * 16 + c];
    #pragma unroll
    for (int mf = 0; mf < 4; ++mf) {
      #pragma unroll
      for (int i = 0; i < 4; ++i) {
        int row = m0 + wm * 64 + mf * 16 + 4 * g + i;
        int col = n0 + wn * 64 + nf * 16 + c;
        float v = acc[mf][nf][i] + bb;
        H[(long)row * HID + col] = f2bf(fmaxf(v, 0.f));
      }
    }
  }
}

// ---------------- GEMM2 (params) fused with per-lane spline ----------------
// M=8192, Npad=12288, K=1024. Tile 256x192 (4 features), 8 waves (2x4),
// wave = 128 rows x 48 cols (1 feature).
__global__ __launch_bounds__(512, 2) void k_gemm2_spline(
    const unsigned short* __restrict__ Hb, const unsigned short* __restrict__ W2T,
    const float* __restrict__ b2, const float* __restrict__ inp,
    float* __restrict__ outp, float* __restrict__ ladw) {
  __shared__ __align__(16) char sm[57344];  // A 32KB @0, B 24KB @32768
  char* smA = sm;
  char* smB = sm + 32768;
  const int tid = threadIdx.x;
  const int lane = tid & 63, wid = tid >> 6;
  const int c = lane & 15, g = lane >> 4;
  const int wm = wid >> 2, wn = wid & 3;
  const long m0 = (long)blockIdx.x * 256;
  const int bn = blockIdx.y;
  const int n0 = bn * 192;  // padded-col base

  f32x4 zero = {0.f, 0.f, 0.f, 0.f};
  f32x4 acc[8][3];
  #pragma unroll
  for (int a = 0; a < 8; ++a)
    #pragma unroll
    for (int b = 0; b < 3; ++b) acc[a][b] = zero;

  for (int ks = 0; ks < 16; ++ks) {
    #pragma unroll
    for (int j = 0; j < 4; ++j) {          // A: 2048 slots (256 rows x 8)
      int s0 = j * 512 + wid * 64;
      int s = s0 + lane;
      int row = s >> 3, kb = (s & 7) ^ (row & 7);
      gload16(Hb + (m0 + row) * 1024L + ks * 64 + kb * 8, smA + s0 * 16);
    }
    #pragma unroll
    for (int j = 0; j < 3; ++j) {          // B: 1536 slots (192 rows x 8)
      int s0 = j * 512 + wid * 64;
      int s = s0 + lane;
      int row = s >> 3, kb = (s & 7) ^ (row & 7);
      gload16(W2T + (long)(n0 + row) * 1024L + ks * 64 + kb * 8, smB + s0 * 16);
    }
    __syncthreads();
    #pragma unroll
    for (int kk = 0; kk < 2; ++kk) {
      bf16x8 av[8], bv[3];
      int kbl = kk * 4 + g;
      #pragma unroll
      for (int mf = 0; mf < 8; ++mf) {
        int row = wm * 128 + mf * 16 + c;
        av[mf] = *(const bf16x8*)(smA + row * 128 + ((kbl ^ (row & 7)) << 4));
      }
      #pragma unroll
      for (int nf = 0; nf < 3; ++nf) {
        int col = wn * 48 + nf * 16 + c;
        bv[nf] = *(const bf16x8*)(smB + col * 128 + ((kbl ^ (col & 7)) << 4));
      }
      #pragma unroll
      for (int mf = 0; mf < 8; ++mf)
        #pragma unroll
        for (int nf = 0; nf < 3; ++nf)
          acc[mf][nf] = __builtin_amdgcn_mfma_f32_16x16x32_bf16(
              av[mf], bv[nf], acc[mf][nf], 0, 0, 0);
    }
    __syncthreads();
  }

  // ---- transposed epilogue: per-wave LDS region, per-lane spline ----
  // region: 64 rows x 17 f32 (pad 17 => conflict-free transposed reads)
  float* stg = (float*)(sm + wid * (64 * 17 * 4));
  const int t = bn * 4 + wn;               // global transform-feature id
  const float* b2t = b2 + t * PPF;
  const float bw = b2t[c];
  const float bh = b2t[16 + c];
  const float bd = (c < 15) ? b2t[32 + c] : 0.f;

  #pragma unroll
  for (int ch = 0; ch < 2; ++ch) {
    float kw[17], kh[17], dv[17];
    // --- widths ---
    #pragma unroll
    for (int mf4 = 0; mf4 < 4; ++mf4)
      #pragma unroll
      for (int i = 0; i < 4; ++i)
        stg[(mf4 * 16 + 4 * g + i) * 17 + c] = acc[ch * 4 + mf4][0][i] + bw;
    __syncthreads();
    {
      float u[16];
      #pragma unroll
      for (int k = 0; k < 16; ++k) u[k] = stg[lane * 17 + k];
      float mx = u[0];
      #pragma unroll
      for (int k = 1; k < 16; ++k) mx = fmaxf(mx, u[k]);
      float e[16], s = 0.f;
      #pragma unroll
      for (int k = 0; k < 16; ++k) { e[k] = __expf(u[k] - mx); s += e[k]; }
      float inv = (1.f - MIN_W * 16.f) / s;
      float cum = 0.f;
      kw[0] = -TBOUND;
      #pragma unroll
      for (int k = 0; k < 15; ++k) {
        cum += MIN_W + e[k] * inv;
        kw[k + 1] = fmaf(2.f * TBOUND, cum, -TBOUND);
      }
      kw[16] = TBOUND;
    }
    __syncthreads();
    // --- heights ---
    #pragma unroll
    for (int mf4 = 0; mf4 < 4; ++mf4)
      #pragma unroll
      for (int i = 0; i < 4; ++i)
        stg[(mf4 * 16 + 4 * g + i) * 17 + c] = acc[ch * 4 + mf4][1][i] + bh;
    __syncthreads();
    {
      float u[16];
      #pragma unroll
      for (int k = 0; k < 16; ++k) u[k] = stg[lane * 17 + k];
      float mx = u[0];
      #pragma unroll
      for (int k = 1; k < 16; ++k) mx = fmaxf(mx, u[k]);
      float e[16], s = 0.f;
      #pragma unroll
      for (int k = 0; k < 16; ++k) { e[k] = __expf(u[k] - mx); s += e[k]; }
      float inv = (1.f - MIN_H * 16.f) / s;
      float cum = 0.f;
      kh[0] = -TBOUND;
      #pragma unroll
      for (int k = 0; k < 15; ++k) {
        cum += MIN_H + e[k] * inv;
        kh[k + 1] = fmaf(2.f * TBOUND, cum, -TBOUND);
      }
      kh[16] = TBOUND;
    }
    __syncthreads();
    // --- derivatives ---
    #pragma unroll
    for (int mf4 = 0; mf4 < 4; ++mf4)
      #pragma unroll
      for (int i = 0; i < 4; ++i)
        stg[(mf4 * 16 + 4 * g + i) * 17 + c] = acc[ch * 4 + mf4][2][i] + bd;
    __syncthreads();
    {
      #pragma unroll
      for (int k = 0; k < 15; ++k) {
        float u = stg[lane * 17 + k];
        float sp = (u > 0.f) ? (u + log1pf(__expf(-u))) : log1pf(__expf(u));
        dv[k + 1] = MIN_D + sp;
      }
      dv[0] = 1.f;
      dv[16] = 1.f;
    }
    __syncthreads();

    // --- per-lane spline eval, one row per lane ---
    long r = m0 + wm * 128 + ch * 64 + lane;
    float x = inp[r * FEAT + 2 * t];
    float xc = fminf(fmaxf(x, -TBOUND), TBOUND);
    float in_cw = kw[0], in_w = kw[1] - kw[0];
    float in_ch = kh[0], in_h = kh[1] - kh[0];
    float d0 = dv[0], d1 = dv[1];
    #pragma unroll
    for (int k = 1; k < 16; ++k) {
      bool sel = xc >= kw[k];
      if (sel) {
        in_cw = kw[k]; in_w = kw[k + 1] - kw[k];
        in_ch = kh[k]; in_h = kh[k + 1] - kh[k];
        d0 = dv[k]; d1 = dv[k + 1];
      }
    }
    float dlt = in_h / in_w;
    float th = (xc - in_cw) / in_w;
    float omt = 1.f - th, t1m = th * omt;
    float den = dlt + (d0 + d1 - 2.f * dlt) * t1m;
    float num = in_h * (dlt * th * th + d0 * t1m);
    float y = in_ch + num / den;
    float dn = dlt * dlt * (d1 * th * th + 2.f * dlt * t1m + d0 * omt * omt);
    float lad = __logf(dn) - 2.f * __logf(den);
    bool inside = (x >= -TBOUND) && (x <= TBOUND);
    y = inside ? y : x;
    lad = inside ? lad : 0.f;
    outp[r * FEAT + 2 * t] = y;
    ladw[r * NTR + t] = lad;
  }
}

// ---------------- lad reduction: 256 -> 1 per batch row ----------------
__global__ void k_reduce_lad(const float* __restrict__ ladw,
                             float* __restrict__ lado) {
  int wid = threadIdx.x >> 6, lane = threadIdx.x & 63;
  long b = (long)blockIdx.x * 4 + wid;
  const float4* p = (const float4*)(ladw + b * NTR);
  float4 v = p[lane];
  float s = v.x + v.y + v.z + v.w;
  #pragma unroll
  for (int d = 1; d < 64; d <<= 1) s += __shfl_xor(s, d, 64);
  if (lane == 0) lado[b] = s;
}

extern "C" void kernel_launch(void* const* d_in, const int* in_sizes, int n_in,
                              void* d_out, int out_size, void* d_ws, size_t ws_size,
                              hipStream_t stream) {
  const float* inp = (const float*)d_in[0];
  const float* W1  = (const float*)d_in[1];
  const float* b1  = (const float*)d_in[2];
  const float* W2  = (const float*)d_in[3];
  const float* b2  = (const float*)d_in[4];
  float* outp = (float*)d_out;
  float* lado = outp + (long)BATCH * FEAT;

  // workspace layout (~52.5 MB)
  char* ws = (char*)d_ws;
  unsigned short* Hb   = (unsigned short*)(ws);              // 16,777,216 B
  unsigned short* idbf = (unsigned short*)(ws + 16777216);   //  4,194,304 B
  unsigned short* W1T  = (unsigned short*)(ws + 20971520);   //    524,288 B
  unsigned short* W2T  = (unsigned short*)(ws + 21495808);   // 25,165,824 B
  float*          ladw = (float*)(ws + 46661632);            //  8,388,608 B

  k_pack_inputs<<<dim3(BATCH), dim3(256), 0, stream>>>(inp, idbf, outp);
  k_pack_w1t<<<dim3(16, 4), dim3(256), 0, stream>>>(W1, W1T);
  k_pack_w2t<<<dim3(188, 16), dim3(256), 0, stream>>>(W2, W2T);
  k_pad_w2t<<<dim3(1024), dim3(256), 0, stream>>>(W2T);
  k_gemm1<<<dim3(64, 8), dim3(256), 0, stream>>>(idbf, W1T, b1, Hb);
  k_gemm2_spline<<<dim3(32, 64), dim3(512), 0, stream>>>(Hb, W2T, b2, inp, outp, ladw);
  k_reduce_lad<<<dim3(2048), dim3(256), 0, stream>>>(ladw, lado);
}

// Round 3
// 354.343 us; speedup vs baseline: 2.1530x; 1.3884x over previous
//
#include <hip/hip_runtime.h>

#define BATCH 8192
#define FEAT  512
#define NID   256
#define NTR   256
#define HID   1024
#define PPF   47       // params per transform feature (3*16-1)
#define PPFP  48       // padded to 48
#define NOUT  (NTR*PPF)    // 12032
#define TBOUND 3.0f
#define MIN_W 0.001f
#define MIN_H 0.001f
#define MIN_D 0.001f

typedef __bf16 bf16x8 __attribute__((ext_vector_type(8)));
typedef float  f32x4  __attribute__((ext_vector_type(4)));

__device__ __forceinline__ unsigned short f2bf(float f) {
  unsigned u = __float_as_uint(f);
  u += 0x7FFFu + ((u >> 16) & 1u);   // RNE
  return (unsigned short)(u >> 16);
}

// async global->LDS, 16B per lane. LDS dest must be wave-uniform base
// (HW adds lane*16); global source is per-lane.
__device__ __forceinline__ void gload16(const void* g, void* l) {
  __builtin_amdgcn_global_load_lds(
      (const __attribute__((address_space(1))) void*)g,
      (__attribute__((address_space(3))) void*)l, 16, 0, 0);
}

// ---------------- pack kernels ----------------

__global__ void k_pack_inputs(const float* __restrict__ in,
                              unsigned short* __restrict__ idbf,
                              float* __restrict__ outp) {
  int b = blockIdx.x;
  int j = threadIdx.x;            // 0..255
  float v = in[b * FEAT + 2 * j + 1];
  idbf[b * NID + j] = f2bf(v);
  outp[b * FEAT + 2 * j + 1] = v;
}

// W1 [256][1024] f32 -> W1T [1024][256] bf16
__global__ void k_pack_w1t(const float* __restrict__ W1,
                           unsigned short* __restrict__ W1T) {
  __shared__ unsigned short tl[64][65];
  int n0 = blockIdx.x * 64, k0 = blockIdx.y * 64;
  int c = threadIdx.x & 63, r4 = threadIdx.x >> 6;
  #pragma unroll
  for (int i = 0; i < 16; ++i) {
    int kk = r4 + i * 4;
    tl[kk][c] = f2bf(W1[(k0 + kk) * HID + n0 + c]);
  }
  __syncthreads();
  #pragma unroll
  for (int i = 0; i < 16; ++i) {
    int nn = r4 + i * 4;
    W1T[(n0 + nn) * NID + k0 + c] = tl[c][nn];
  }
}

// W2 [1024][12032] f32 -> W2T [12288][1024] bf16 (padded)
__global__ void k_pack_w2t(const float* __restrict__ W2,
                           unsigned short* __restrict__ W2T) {
  __shared__ unsigned short tl[64][65];
  int ns0 = blockIdx.x * 64, k0 = blockIdx.y * 64;
  int c = threadIdx.x & 63, r4 = threadIdx.x >> 6;
  #pragma unroll
  for (int i = 0; i < 16; ++i) {
    int kk = r4 + i * 4;
    tl[kk][c] = f2bf(W2[(k0 + kk) * (long)NOUT + ns0 + c]);
  }
  __syncthreads();
  #pragma unroll
  for (int i = 0; i < 16; ++i) {
    int nn = r4 + i * 4;
    int ns = ns0 + nn;
    int nd = (ns / PPF) * PPFP + (ns % PPF);
    W2T[(long)nd * HID + k0 + c] = tl[c][nn];
  }
}

__global__ void k_pad_w2t(unsigned short* __restrict__ W2T) {
  int idx = blockIdx.x * 256 + threadIdx.x;  // 256 features * 1024 k
  int f = idx >> 10, k = idx & 1023;
  W2T[((long)(f * PPFP + PPF)) * HID + k] = 0;
}

// ---------------- GEMM1: h = relu(idbf @ W1 + b1), bf16 out ----------------
// M=8192 K=256 N=1024, tiles 128x128, BK=64, 4 waves (2x2), dbuf 2-phase
__global__ __launch_bounds__(256, 2) void k_gemm1(
    const unsigned short* __restrict__ A, const unsigned short* __restrict__ Bw,
    const float* __restrict__ b1, unsigned short* __restrict__ H) {
  __shared__ __align__(16) char sm[65536];  // 2 x (A 16KB + B 16KB)
  const int tid = threadIdx.x;
  const int lane = tid & 63, wid = tid >> 6;
  const int c = lane & 15, g = lane >> 4;
  const int wm = wid >> 1, wn = wid & 1;
  const int m0 = blockIdx.x * 128, n0 = blockIdx.y * 128;

  f32x4 zero = {0.f, 0.f, 0.f, 0.f};
  f32x4 acc[4][4];
  #pragma unroll
  for (int a = 0; a < 4; ++a)
    #pragma unroll
    for (int b = 0; b < 4; ++b) acc[a][b] = zero;

  #define G1_STAGE(half, ks)                                                   \
    {                                                                          \
      char* bA = sm + (half) * 32768;                                          \
      char* bB = bA + 16384;                                                   \
      _Pragma("unroll")                                                        \
      for (int j = 0; j < 4; ++j) {                                            \
        int s0 = j * 256 + wid * 64;                                           \
        int s = s0 + lane;                                                     \
        int row = s >> 3, kb = (s & 7) ^ (row & 7);                            \
        gload16(A + (long)(m0 + row) * NID + (ks) * 64 + kb * 8, bA + s0 * 16);\
        gload16(Bw + (long)(n0 + row) * NID + (ks) * 64 + kb * 8, bB + s0 * 16);\
      }                                                                        \
    }

  G1_STAGE(0, 0);
  __syncthreads();
  for (int ks = 0; ks < 4; ++ks) {
    int cur = ks & 1;
    if (ks < 3) G1_STAGE(cur ^ 1, ks + 1);
    char* bA = sm + cur * 32768;
    char* bB = bA + 16384;
    #pragma unroll
    for (int kk = 0; kk < 2; ++kk) {
      bf16x8 av[4], bv[4];
      int kbl = kk * 4 + g;
      #pragma unroll
      for (int mf = 0; mf < 4; ++mf) {
        int row = wm * 64 + mf * 16 + c;
        av[mf] = *(const bf16x8*)(bA + row * 128 + ((kbl ^ (row & 7)) << 4));
      }
      #pragma unroll
      for (int nf = 0; nf < 4; ++nf) {
        int col = wn * 64 + nf * 16 + c;
        bv[nf] = *(const bf16x8*)(bB + col * 128 + ((kbl ^ (col & 7)) << 4));
      }
      #pragma unroll
      for (int mf = 0; mf < 4; ++mf)
        #pragma unroll
        for (int nf = 0; nf < 4; ++nf)
          acc[mf][nf] = __builtin_amdgcn_mfma_f32_16x16x32_bf16(
              av[mf], bv[nf], acc[mf][nf], 0, 0, 0);
    }
    __syncthreads();
  }
  #pragma unroll
  for (int nf = 0; nf < 4; ++nf) {
    float bb = b1[n0 + wn * 64 + nf * 16 + c];
    #pragma unroll
    for (int mf = 0; mf < 4; ++mf) {
      #pragma unroll
      for (int i = 0; i < 4; ++i) {
        int row = m0 + wm * 64 + mf * 16 + 4 * g + i;
        int col = n0 + wn * 64 + nf * 16 + c;
        float v = acc[mf][nf][i] + bb;
        H[(long)row * HID + col] = f2bf(fmaxf(v, 0.f));
      }
    }
  }
}

// ---------------- GEMM2 (params) fused with per-lane spline ----------------
// M=8192, Npad=12288, K=1024. Tile 128x192 (4 features), 8 waves (2x4),
// wave = 64 rows x 48 cols (1 feature). Double-buffered 2-phase K-loop.
__global__ __launch_bounds__(512, 4) void k_gemm2_spline(
    const unsigned short* __restrict__ Hb, const unsigned short* __restrict__ W2T,
    const float* __restrict__ b2, const float* __restrict__ inp,
    float* __restrict__ outp, float* __restrict__ ladw) {
  __shared__ __align__(16) char sm[81920];  // 2 x (A 16KB + B 24KB)
  const int tid = threadIdx.x;
  const int lane = tid & 63, wid = tid >> 6;
  const int c = lane & 15, g = lane >> 4;
  const int wm = wid >> 2, wn = wid & 3;
  const long m0 = (long)blockIdx.x * 128;
  const int bn = blockIdx.y;
  const int n0 = bn * 192;  // padded-col base

  f32x4 zero = {0.f, 0.f, 0.f, 0.f};
  f32x4 acc[4][3];
  #pragma unroll
  for (int a = 0; a < 4; ++a)
    #pragma unroll
    for (int b = 0; b < 3; ++b) acc[a][b] = zero;

  #define G2_STAGE(half, ks)                                                   \
    {                                                                          \
      char* bA = sm + (half) * 40960;                                          \
      char* bB = bA + 16384;                                                   \
      _Pragma("unroll")                                                        \
      for (int j = 0; j < 2; ++j) {  /* A: 1024 slots (128 rows x 8) */        \
        int s0 = j * 512 + wid * 64;                                           \
        int s = s0 + lane;                                                     \
        int row = s >> 3, kb = (s & 7) ^ (row & 7);                            \
        gload16(Hb + (m0 + row) * 1024L + (ks) * 64 + kb * 8, bA + s0 * 16);   \
      }                                                                        \
      _Pragma("unroll")                                                        \
      for (int j = 0; j < 3; ++j) {  /* B: 1536 slots (192 rows x 8) */        \
        int s0 = j * 512 + wid * 64;                                           \
        int s = s0 + lane;                                                     \
        int row = s >> 3, kb = (s & 7) ^ (row & 7);                            \
        gload16(W2T + (long)(n0 + row) * 1024L + (ks) * 64 + kb * 8,           \
                bB + s0 * 16);                                                 \
      }                                                                        \
    }

  G2_STAGE(0, 0);
  __syncthreads();
  for (int ks = 0; ks < 16; ++ks) {
    int cur = ks & 1;
    if (ks < 15) G2_STAGE(cur ^ 1, ks + 1);
    char* bA = sm + cur * 40960;
    char* bB = bA + 16384;
    #pragma unroll
    for (int kk = 0; kk < 2; ++kk) {
      bf16x8 av[4], bv[3];
      int kbl = kk * 4 + g;
      #pragma unroll
      for (int mf = 0; mf < 4; ++mf) {
        int row = wm * 64 + mf * 16 + c;
        av[mf] = *(const bf16x8*)(bA + row * 128 + ((kbl ^ (row & 7)) << 4));
      }
      #pragma unroll
      for (int nf = 0; nf < 3; ++nf) {
        int col = wn * 48 + nf * 16 + c;
        bv[nf] = *(const bf16x8*)(bB + col * 128 + ((kbl ^ (col & 7)) << 4));
      }
      #pragma unroll
      for (int mf = 0; mf < 4; ++mf)
        #pragma unroll
        for (int nf = 0; nf < 3; ++nf)
          acc[mf][nf] = __builtin_amdgcn_mfma_f32_16x16x32_bf16(
              av[mf], bv[nf], acc[mf][nf], 0, 0, 0);
    }
    __syncthreads();
  }

  // ---- transposed epilogue: per-wave LDS region, per-lane spline ----
  // region: 64 rows x 17 f32 (pad 17 => conflict-free transposed reads)
  float* stg = (float*)(sm + wid * (64 * 17 * 4));
  const int t = bn * 4 + wn;               // global transform-feature id
  const float* b2t = b2 + t * PPF;
  const float bw = b2t[c];
  const float bh = b2t[16 + c];
  const float bd = (c < 15) ? b2t[32 + c] : 0.f;

  float kw[17], kh[17], dv[17];
  // --- widths ---
  #pragma unroll
  for (int mf = 0; mf < 4; ++mf)
    #pragma unroll
    for (int i = 0; i < 4; ++i)
      stg[(mf * 16 + 4 * g + i) * 17 + c] = acc[mf][0][i] + bw;
  __syncthreads();
  {
    float u[16];
    #pragma unroll
    for (int k = 0; k < 16; ++k) u[k] = stg[lane * 17 + k];
    float mx = u[0];
    #pragma unroll
    for (int k = 1; k < 16; ++k) mx = fmaxf(mx, u[k]);
    float e[16], s = 0.f;
    #pragma unroll
    for (int k = 0; k < 16; ++k) { e[k] = __expf(u[k] - mx); s += e[k]; }
    float inv = (1.f - MIN_W * 16.f) / s;
    float cum = 0.f;
    kw[0] = -TBOUND;
    #pragma unroll
    for (int k = 0; k < 15; ++k) {
      cum += MIN_W + e[k] * inv;
      kw[k + 1] = fmaf(2.f * TBOUND, cum, -TBOUND);
    }
    kw[16] = TBOUND;
  }
  __syncthreads();
  // --- heights ---
  #pragma unroll
  for (int mf = 0; mf < 4; ++mf)
    #pragma unroll
    for (int i = 0; i < 4; ++i)
      stg[(mf * 16 + 4 * g + i) * 17 + c] = acc[mf][1][i] + bh;
  __syncthreads();
  {
    float u[16];
    #pragma unroll
    for (int k = 0; k < 16; ++k) u[k] = stg[lane * 17 + k];
    float mx = u[0];
    #pragma unroll
    for (int k = 1; k < 16; ++k) mx = fmaxf(mx, u[k]);
    float e[16], s = 0.f;
    #pragma unroll
    for (int k = 0; k < 16; ++k) { e[k] = __expf(u[k] - mx); s += e[k]; }
    float inv = (1.f - MIN_H * 16.f) / s;
    float cum = 0.f;
    kh[0] = -TBOUND;
    #pragma unroll
    for (int k = 0; k < 15; ++k) {
      cum += MIN_H + e[k] * inv;
      kh[k + 1] = fmaf(2.f * TBOUND, cum, -TBOUND);
    }
    kh[16] = TBOUND;
  }
  __syncthreads();
  // --- derivatives ---
  #pragma unroll
  for (int mf = 0; mf < 4; ++mf)
    #pragma unroll
    for (int i = 0; i < 4; ++i)
      stg[(mf * 16 + 4 * g + i) * 17 + c] = acc[mf][2][i] + bd;
  __syncthreads();
  {
    #pragma unroll
    for (int k = 0; k < 15; ++k) {
      float u = stg[lane * 17 + k];
      float sp = (u > 0.f) ? (u + log1pf(__expf(-u))) : log1pf(__expf(u));
      dv[k + 1] = MIN_D + sp;
    }
    dv[0] = 1.f;
    dv[16] = 1.f;
  }

  // --- per-lane spline eval, one row per lane ---
  long r = m0 + wm * 64 + lane;
  float x = inp[r * FEAT + 2 * t];
  float xc = fminf(fmaxf(x, -TBOUND), TBOUND);
  float in_cw = kw[0], in_w = kw[1] - kw[0];
  float in_ch = kh[0], in_h = kh[1] - kh[0];
  float d0 = dv[0], d1 = dv[1];
  #pragma unroll
  for (int k = 1; k < 16; ++k) {
    bool sel = xc >= kw[k];
    if (sel) {
      in_cw = kw[k]; in_w = kw[k + 1] - kw[k];
      in_ch = kh[k]; in_h = kh[k + 1] - kh[k];
      d0 = dv[k]; d1 = dv[k + 1];
    }
  }
  float dlt = in_h / in_w;
  float th = (xc - in_cw) / in_w;
  float omt = 1.f - th, t1m = th * omt;
  float den = dlt + (d0 + d1 - 2.f * dlt) * t1m;
  float num = in_h * (dlt * th * th + d0 * t1m);
  float y = in_ch + num / den;
  float dn = dlt * dlt * (d1 * th * th + 2.f * dlt * t1m + d0 * omt * omt);
  float lad = __logf(dn) - 2.f * __logf(den);
  bool inside = (x >= -TBOUND) && (x <= TBOUND);
  y = inside ? y : x;
  lad = inside ? lad : 0.f;
  outp[r * FEAT + 2 * t] = y;
  ladw[r * NTR + t] = lad;
}

// ---------------- lad reduction: 256 -> 1 per batch row ----------------
__global__ void k_reduce_lad(const float* __restrict__ ladw,
                             float* __restrict__ lado) {
  int wid = threadIdx.x >> 6, lane = threadIdx.x & 63;
  long b = (long)blockIdx.x * 4 + wid;
  const float4* p = (const float4*)(ladw + b * NTR);
  float4 v = p[lane];
  float s = v.x + v.y + v.z + v.w;
  #pragma unroll
  for (int d = 1; d < 64; d <<= 1) s += __shfl_xor(s, d, 64);
  if (lane == 0) lado[b] = s;
}

extern "C" void kernel_launch(void* const* d_in, const int* in_sizes, int n_in,
                              void* d_out, int out_size, void* d_ws, size_t ws_size,
                              hipStream_t stream) {
  const float* inp = (const float*)d_in[0];
  const float* W1  = (const float*)d_in[1];
  const float* b1  = (const float*)d_in[2];
  const float* W2  = (const float*)d_in[3];
  const float* b2  = (const float*)d_in[4];
  float* outp = (float*)d_out;
  float* lado = outp + (long)BATCH * FEAT;

  // workspace layout (~52.5 MB)
  char* ws = (char*)d_ws;
  unsigned short* Hb   = (unsigned short*)(ws);              // 16,777,216 B
  unsigned short* idbf = (unsigned short*)(ws + 16777216);   //  4,194,304 B
  unsigned short* W1T  = (unsigned short*)(ws + 20971520);   //    524,288 B
  unsigned short* W2T  = (unsigned short*)(ws + 21495808);   // 25,165,824 B
  float*          ladw = (float*)(ws + 46661632);            //  8,388,608 B

  k_pack_inputs<<<dim3(BATCH), dim3(256), 0, stream>>>(inp, idbf, outp);
  k_pack_w1t<<<dim3(16, 4), dim3(256), 0, stream>>>(W1, W1T);
  k_pack_w2t<<<dim3(188, 16), dim3(256), 0, stream>>>(W2, W2T);
  k_pad_w2t<<<dim3(1024), dim3(256), 0, stream>>>(W2T);
  k_gemm1<<<dim3(64, 8), dim3(256), 0, stream>>>(idbf, W1T, b1, Hb);
  k_gemm2_spline<<<dim3(64, 64), dim3(512), 0, stream>>>(Hb, W2T, b2, inp, outp, ladw);
  k_reduce_lad<<<dim3(2048), dim3(256), 0, stream>>>(ladw, lado);
}